// Round 1
// baseline (434.141 us; speedup 1.0000x reference)
//
#include <hip/hip_runtime.h>
#include <stdint.h>

typedef int   v4i __attribute__((ext_vector_type(4)));
typedef float v4f __attribute__((ext_vector_type(4)));

#define TOK_M 8192   // B*S = 4*2048
#define DIM_K 4096   // IN
#define DIM_N 4096   // OUT
#define BM 128
#define BN 128
#define BK 64

#define GLOAD_LDS16(gsrc, ldst)                                                        \
  __builtin_amdgcn_global_load_lds((const __attribute__((address_space(1))) void*)(gsrc), \
                                   (__attribute__((address_space(3))) void*)(ldst), 16, 0, 0)

// ---------------------------------------------------------------------------
// Kernel 1: weight int32 -> int8 pack + per-row sums (w is [N][K] = [OUT][IN])
// ---------------------------------------------------------------------------
__global__ __launch_bounds__(256) void k_pack_w(const int* __restrict__ w,
                                                int8_t* __restrict__ wq,
                                                float* __restrict__ wsumf) {
    __shared__ int sred[4];
    const int row = blockIdx.x;
    const int tid = threadIdx.x;
    const int4* src = (const int4*)(w + (size_t)row * DIM_K) + tid * 4;
    int sum = 0;
    unsigned packed[4];
#pragma unroll
    for (int c = 0; c < 4; ++c) {
        int4 iv = src[c];
        sum += iv.x + iv.y + iv.z + iv.w;
        packed[c] = (unsigned)(iv.x & 255) | ((unsigned)(iv.y & 255) << 8) |
                    ((unsigned)(iv.z & 255) << 16) | ((unsigned)(iv.w & 255) << 24);
    }
    int4 outv = make_int4((int)packed[0], (int)packed[1], (int)packed[2], (int)packed[3]);
    *((int4*)(wq + (size_t)row * DIM_K) + tid) = outv;
#pragma unroll
    for (int off = 32; off; off >>= 1) sum += __shfl_xor(sum, off);
    if ((tid & 63) == 0) sred[tid >> 6] = sum;
    __syncthreads();
    if (tid == 0) wsumf[row] = (float)(sred[0] + sred[1] + sred[2] + sred[3]);
}

// ---------------------------------------------------------------------------
// Kernel 2: per-token dynamic quant. x [TOK_M][K] fp32 -> q int8, plus
//   sA[m] = scale_tok, sB[m] = scale_tok*zp, sC[m] = scale_tok*(qsum - K*zp)
// ---------------------------------------------------------------------------
__global__ __launch_bounds__(256) void k_quant(const float* __restrict__ x,
                                               int8_t* __restrict__ q,
                                               float* __restrict__ sA,
                                               float* __restrict__ sB,
                                               float* __restrict__ sC) {
    __shared__ float redf[8];
    __shared__ int   redi[4];
    __shared__ float bcast[2];
    const int tok = blockIdx.x;
    const int tid = threadIdx.x;
    const v4f* xr = (const v4f*)(x + (size_t)tok * DIM_K) + tid * 4;
    v4f v[4];
    float mn = 0.0f, mx = 0.0f;   // jnp: min(.,0) / max(.,0)
#pragma unroll
    for (int c = 0; c < 4; ++c) {
        v[c] = xr[c];
#pragma unroll
        for (int j = 0; j < 4; ++j) {
            mn = fminf(mn, v[c][j]);
            mx = fmaxf(mx, v[c][j]);
        }
    }
#pragma unroll
    for (int off = 32; off; off >>= 1) {
        mn = fminf(mn, __shfl_xor(mn, off));
        mx = fmaxf(mx, __shfl_xor(mx, off));
    }
    const int wid = tid >> 6;
    if ((tid & 63) == 0) { redf[wid] = mn; redf[4 + wid] = mx; }
    __syncthreads();
    if (tid == 0) {
        float m0 = fminf(fminf(redf[0], redf[1]), fminf(redf[2], redf[3]));
        float m1 = fmaxf(fmaxf(redf[4], redf[5]), fmaxf(redf[6], redf[7]));
        float scale = fmaxf((m1 - m0) / 255.0f, 1.1920928955078125e-07f);
        float zpf = -128.0f - rintf(m0 / scale);
        zpf = fminf(fmaxf(zpf, -128.0f), 127.0f);
        bcast[0] = scale; bcast[1] = zpf;
    }
    __syncthreads();
    const float scale = bcast[0];
    const float zpf   = bcast[1];
    const float inv   = 1.0f / scale;
    int qs = 0;
    unsigned packed[4];
#pragma unroll
    for (int c = 0; c < 4; ++c) {
        unsigned p = 0;
#pragma unroll
        for (int j = 0; j < 4; ++j) {
            float qf = rintf(v[c][j] * inv) + zpf;
            qf = fminf(fmaxf(qf, -128.0f), 127.0f);
            int qi = (int)qf;
            qs += qi;
            p |= ((unsigned)(qi & 255)) << (8 * j);
        }
        packed[c] = p;
    }
    *((int4*)(q + (size_t)tok * DIM_K) + tid) =
        make_int4((int)packed[0], (int)packed[1], (int)packed[2], (int)packed[3]);
#pragma unroll
    for (int off = 32; off; off >>= 1) qs += __shfl_xor(qs, off);
    if ((tid & 63) == 0) redi[wid] = qs;
    __syncthreads();
    if (tid == 0) {
        int qtot = redi[0] + redi[1] + redi[2] + redi[3];
        float t = (float)qtot - 4096.0f * zpf;
        sA[tok] = scale;
        sB[tok] = scale * zpf;
        sC[tok] = scale * t;
    }
}

// ---------------------------------------------------------------------------
// Kernel 3: int8 GEMM, m97 structure. A=[M][K] int8 (q), B=[N][K] int8 (wq),
// C[m][n] = scales[n] * ( sA[m]*acc - sB[m]*wsum[n] - sC[m]*zeros[n] )
// ---------------------------------------------------------------------------
__global__ __launch_bounds__(256) void k_gemm(const int8_t* __restrict__ A,
                                              const int8_t* __restrict__ B,
                                              const float* __restrict__ sA,
                                              const float* __restrict__ sB,
                                              const float* __restrict__ sC,
                                              const float* __restrict__ wsumf,
                                              const float* __restrict__ scales,
                                              const float* __restrict__ zeros,
                                              float* __restrict__ out) {
    __shared__ int8_t As[BM * BK];   // 8 KB, linear (global_load_lds requirement)
    __shared__ int8_t Bs[BN * BK];   // 8 KB
    const int tid = threadIdx.x;
    const int w = tid >> 6;
    const int l = tid & 63;
    const int m0 = blockIdx.y * BM;
    const int n0 = blockIdx.x * BN;

    // staging: 2 chunks of 16B per thread per matrix; wave-contiguous layout
    const int o0 = (w * 2 + 0) * 1024 + l * 16;
    const int o1 = (w * 2 + 1) * 1024 + l * 16;
    const int8_t* a0 = A + (size_t)(m0 + (o0 >> 6)) * DIM_K + (o0 & 63);
    const int8_t* a1 = A + (size_t)(m0 + (o1 >> 6)) * DIM_K + (o1 & 63);
    const int8_t* b0 = B + (size_t)(n0 + (o0 >> 6)) * DIM_K + (o0 & 63);
    const int8_t* b1 = B + (size_t)(n0 + (o1 >> 6)) * DIM_K + (o1 & 63);

    const int wr = (w >> 1) * 64;    // wave row offset in tile
    const int wc = (w & 1) * 64;     // wave col offset in tile
    const int lr = l & 15;
    const int lg = (l >> 4) * 16;    // 16-byte K-chunk within the 64B row

    v4i acc[4][4] = {};

    for (int k0 = 0; k0 < DIM_K; k0 += BK) {
        GLOAD_LDS16(a0 + k0, As + o0);
        GLOAD_LDS16(a1 + k0, As + o1);
        GLOAD_LDS16(b0 + k0, Bs + o0);
        GLOAD_LDS16(b1 + k0, Bs + o1);
        __syncthreads();   // drains vmcnt before barrier (compiler-inserted)

        v4i af[4], bf[4];
#pragma unroll
        for (int mi = 0; mi < 4; ++mi)
            af[mi] = *(const v4i*)(As + (wr + mi * 16 + lr) * BK + lg);
#pragma unroll
        for (int ni = 0; ni < 4; ++ni)
            bf[ni] = *(const v4i*)(Bs + (wc + ni * 16 + lr) * BK + lg);
#pragma unroll
        for (int mi = 0; mi < 4; ++mi)
#pragma unroll
            for (int ni = 0; ni < 4; ++ni)
                acc[mi][ni] = __builtin_amdgcn_mfma_i32_16x16x64_i8(
                    af[mi], bf[ni], acc[mi][ni], 0, 0, 0);
        __syncthreads();
    }

    // epilogue: C/D layout (16x16, dtype-independent): col = l&15, row = (l>>4)*4 + reg
    const int col_l = l & 15;
    const int rg = (l >> 4) * 4;
    float scl[4], zrs[4], wsm[4];
    int gc[4];
#pragma unroll
    for (int ni = 0; ni < 4; ++ni) {
        gc[ni] = n0 + wc + ni * 16 + col_l;
        scl[ni] = scales[gc[ni]];
        zrs[ni] = zeros[gc[ni]];
        wsm[ni] = wsumf[gc[ni]];
    }
#pragma unroll
    for (int mi = 0; mi < 4; ++mi) {
#pragma unroll
        for (int j = 0; j < 4; ++j) {
            const int gr = m0 + wr + mi * 16 + rg + j;
            const float ra = sA[gr];
            const float rb = sB[gr];
            const float rc = sC[gr];
            float* orow = out + (size_t)gr * DIM_N;
#pragma unroll
            for (int ni = 0; ni < 4; ++ni) {
                float accf = (float)acc[mi][ni][j];
                orow[gc[ni]] = scl[ni] * (ra * accf - rb * wsm[ni] - rc * zrs[ni]);
            }
        }
    }
}

// ---------------------------------------------------------------------------
extern "C" void kernel_launch(void* const* d_in, const int* in_sizes, int n_in,
                              void* d_out, int out_size, void* d_ws, size_t ws_size,
                              hipStream_t stream) {
    const float* x      = (const float*)d_in[0];
    const int*   w      = (const int*)d_in[1];     // int8 values uploaded as int32
    const float* scales = (const float*)d_in[2];
    const float* zeros  = (const float*)d_in[3];
    float* out = (float*)d_out;

    uint8_t* ws = (uint8_t*)d_ws;
    int8_t* q  = (int8_t*)ws;                                  // 32 MiB
    int8_t* wq = (int8_t*)(ws + (size_t)TOK_M * DIM_K);        // 16 MiB
    float* fbuf = (float*)(ws + (size_t)TOK_M * DIM_K + (size_t)DIM_N * DIM_K);
    float* sA    = fbuf;
    float* sB    = fbuf + TOK_M;
    float* sC    = fbuf + 2 * TOK_M;
    float* wsumf = fbuf + 3 * TOK_M;

    k_pack_w<<<DIM_N, 256, 0, stream>>>(w, wq, wsumf);
    k_quant<<<TOK_M, 256, 0, stream>>>(x, q, sA, sB, sC);
    dim3 grid(DIM_N / BN, TOK_M / BM);
    k_gemm<<<grid, 256, 0, stream>>>(q, wq, sA, sB, sC, wsumf, scales, zeros, out);
}

// Round 2
// 416.755 us; speedup vs baseline: 1.0417x; 1.0417x over previous
//
#include <hip/hip_runtime.h>
#include <stdint.h>

typedef int   v4i __attribute__((ext_vector_type(4)));
typedef float v4f __attribute__((ext_vector_type(4)));

#define TOK_M 8192   // B*S = 4*2048
#define DIM_K 4096   // IN
#define DIM_N 4096   // OUT

#define GL(src, dst)                                                                   \
  __builtin_amdgcn_global_load_lds((const __attribute__((address_space(1))) void*)(src), \
                                   (__attribute__((address_space(3))) void*)(dst), 16, 0, 0)

// ---------------------------------------------------------------------------
// Kernel 1: weight int32 -> int8 pack + per-row sums. Fully coalesced:
// each load/store instruction covers a contiguous 1KB/4KB span per wave.
// ---------------------------------------------------------------------------
__global__ __launch_bounds__(256) void k_pack_w(const int* __restrict__ w,
                                                int8_t* __restrict__ wq,
                                                float* __restrict__ wsumf) {
    __shared__ int sred[4];
    const int row = blockIdx.x;
    const int tid = threadIdx.x;
    const int4* src = (const int4*)(w + (size_t)row * DIM_K);
    unsigned* dst = (unsigned*)(wq + (size_t)row * DIM_K);
    int sum = 0;
#pragma unroll
    for (int c = 0; c < 4; ++c) {
        int4 iv = src[c * 256 + tid];
        sum += iv.x + iv.y + iv.z + iv.w;
        unsigned p = (unsigned)(iv.x & 255) | ((unsigned)(iv.y & 255) << 8) |
                     ((unsigned)(iv.z & 255) << 16) | ((unsigned)(iv.w & 255) << 24);
        dst[c * 256 + tid] = p;
    }
#pragma unroll
    for (int off = 32; off; off >>= 1) sum += __shfl_xor(sum, off);
    if ((tid & 63) == 0) sred[tid >> 6] = sum;
    __syncthreads();
    if (tid == 0) wsumf[row] = (float)(sred[0] + sred[1] + sred[2] + sred[3]);
}

// ---------------------------------------------------------------------------
// Kernel 2: per-token dynamic quant (coalesced chunked layout).
//   sA[m]=scale, sB[m]=scale*zp, sC[m]=scale*(qsum - K*zp)
// ---------------------------------------------------------------------------
__global__ __launch_bounds__(256) void k_quant(const float* __restrict__ x,
                                               int8_t* __restrict__ q,
                                               float* __restrict__ sA,
                                               float* __restrict__ sB,
                                               float* __restrict__ sC) {
    __shared__ float redf[8];
    __shared__ int   redi[4];
    __shared__ float bcast[2];
    const int tok = blockIdx.x;
    const int tid = threadIdx.x;
    const v4f* xr = (const v4f*)(x + (size_t)tok * DIM_K);
    v4f v[4];
    float mn = 0.0f, mx = 0.0f;   // jnp: min(.,0) / max(.,0)
#pragma unroll
    for (int c = 0; c < 4; ++c) {
        v[c] = xr[c * 256 + tid];
#pragma unroll
        for (int j = 0; j < 4; ++j) {
            mn = fminf(mn, v[c][j]);
            mx = fmaxf(mx, v[c][j]);
        }
    }
#pragma unroll
    for (int off = 32; off; off >>= 1) {
        mn = fminf(mn, __shfl_xor(mn, off));
        mx = fmaxf(mx, __shfl_xor(mx, off));
    }
    const int wid = tid >> 6;
    if ((tid & 63) == 0) { redf[wid] = mn; redf[4 + wid] = mx; }
    __syncthreads();
    if (tid == 0) {
        float m0 = fminf(fminf(redf[0], redf[1]), fminf(redf[2], redf[3]));
        float m1 = fmaxf(fmaxf(redf[4], redf[5]), fmaxf(redf[6], redf[7]));
        float scale = fmaxf((m1 - m0) / 255.0f, 1.1920928955078125e-07f);
        float zpf = -128.0f - rintf(m0 / scale);
        zpf = fminf(fmaxf(zpf, -128.0f), 127.0f);
        bcast[0] = scale; bcast[1] = zpf;
    }
    __syncthreads();
    const float scale = bcast[0];
    const float zpf   = bcast[1];
    const float inv   = 1.0f / scale;
    int qs = 0;
    unsigned* qo = (unsigned*)(q + (size_t)tok * DIM_K);
#pragma unroll
    for (int c = 0; c < 4; ++c) {
        unsigned p = 0;
#pragma unroll
        for (int j = 0; j < 4; ++j) {
            float qf = rintf(v[c][j] * inv) + zpf;
            qf = fminf(fmaxf(qf, -128.0f), 127.0f);
            int qi = (int)qf;
            qs += qi;
            p |= ((unsigned)(qi & 255)) << (8 * j);
        }
        qo[c * 256 + tid] = p;
    }
#pragma unroll
    for (int off = 32; off; off >>= 1) qs += __shfl_xor(qs, off);
    if ((tid & 63) == 0) redi[wid] = qs;
    __syncthreads();
    if (tid == 0) {
        int qtot = redi[0] + redi[1] + redi[2] + redi[3];
        sA[tok] = scale;
        sB[tok] = scale * zpf;
        sC[tok] = scale * ((float)qtot - 4096.0f * zpf);
    }
}

// ---------------------------------------------------------------------------
// Kernel 3: int8 GEMM, 256x256 tile, 8 waves, BK=64, triple-buffered LDS,
// counted vmcnt, T2 chunk-XOR swizzle, T5 setprio, T1 XCD swizzle.
// ---------------------------------------------------------------------------
#define MFMA8(mI, afR)                                                                     \
    acc[mI][0] = __builtin_amdgcn_mfma_i32_16x16x64_i8(afR, bf0, acc[mI][0], 0, 0, 0);     \
    acc[mI][1] = __builtin_amdgcn_mfma_i32_16x16x64_i8(afR, bf1, acc[mI][1], 0, 0, 0);     \
    acc[mI][2] = __builtin_amdgcn_mfma_i32_16x16x64_i8(afR, bf2, acc[mI][2], 0, 0, 0);     \
    acc[mI][3] = __builtin_amdgcn_mfma_i32_16x16x64_i8(afR, bf3, acc[mI][3], 0, 0, 0);

__global__ __launch_bounds__(512, 2) void k_gemm(const int8_t* __restrict__ A,
                                                 const int8_t* __restrict__ B,
                                                 const float* __restrict__ sA,
                                                 const float* __restrict__ sB,
                                                 const float* __restrict__ sC,
                                                 const float* __restrict__ wsumf,
                                                 const float* __restrict__ scales,
                                                 const float* __restrict__ zeros,
                                                 float* __restrict__ out) {
    extern __shared__ int8_t lds[];   // 3 bufs x (A 16KB + B 16KB) = 96 KB
    const int tid = threadIdx.x;
    const int l = tid & 63;
    const int wid = tid >> 6;

    // T1: XCD-bijective block swizzle (512 blocks, 512 % 8 == 0)
    const int bswz = (blockIdx.x & 7) * 64 + (blockIdx.x >> 3);
    const int tm = (bswz & 31) * 256;   // M-tile fast-varying within an XCD chunk
    const int tn = (bswz >> 5) * 256;

    // staging: thread -> (row = tid>>2, chunk = tid&3); T2 inverse swizzle on the
    // GLOBAL source so LDS[row][pos] holds global chunk pos ^ ((row>>1)&3).
    const int sr  = tid >> 2;
    const int scg = (tid & 3) ^ ((tid >> 3) & 3);
    const int8_t* aS0 = A + (size_t)(tm + sr) * DIM_K + scg * 16;
    const int8_t* aS1 = A + (size_t)(tm + 128 + sr) * DIM_K + scg * 16;
    const int8_t* bS0 = B + (size_t)(tn + sr) * DIM_K + scg * 16;
    const int8_t* bS1 = B + (size_t)(tn + 128 + sr) * DIM_K + scg * 16;
    const int dA0 = tid * 16;
    const int dA1 = 8192 + tid * 16;

    // read addressing: row i = l&15, K-chunk c = l>>4, swizzled pos
    const int i  = l & 15;
    const int ch = l >> 4;
    const int pos = ch ^ ((i >> 1) & 3);
    const int wm = (wid >> 2) * 128;   // 2 wave-rows
    const int wn = (wid & 3) * 64;     // 4 wave-cols
    const int aOff = (wm + i) * 64 + pos * 16;           // + m*1024
    const int bOff = 16384 + (wn + i) * 64 + pos * 16;   // + n*1024

    v4i acc[8][4] = {};

    // prologue: stage K-tiles 0 and 1 into bufs 0,1
    GL(aS0, lds + dA0);          GL(aS1, lds + dA1);
    GL(bS0, lds + 16384 + dA0);  GL(bS1, lds + 16384 + dA1);
    GL(aS0 + 64, lds + 32768 + dA0);          GL(aS1 + 64, lds + 32768 + dA1);
    GL(bS0 + 64, lds + 32768 + 16384 + dA0);  GL(bS1 + 64, lds + 32768 + 16384 + dA1);
    asm volatile("s_waitcnt vmcnt(4)" ::: "memory");
    __builtin_amdgcn_s_barrier();

    int cb = 0, sb = 2;
    for (int kt = 0; kt < 64; ++kt) {
        const int koff = kt * 64 + 128;            // global K byte offset of tile kt+2
        int8_t* Sc = lds + cb * 32768;
        int8_t* St = lds + sb * 32768;
        const bool doStage = (kt < 62);
        v4i bf0, bf1, bf2, bf3;

        // ---- phase 0: stage A-half0(kt+2); read B frags + A m0,m1 ----
        if (doStage) GL(aS0 + koff, St + dA0);
        bf0 = *(const v4i*)(Sc + bOff);
        bf1 = *(const v4i*)(Sc + bOff + 1024);
        bf2 = *(const v4i*)(Sc + bOff + 2048);
        bf3 = *(const v4i*)(Sc + bOff + 3072);
        {
            v4i a0 = *(const v4i*)(Sc + aOff);
            v4i a1 = *(const v4i*)(Sc + aOff + 1024);
            __builtin_amdgcn_sched_barrier(0);
            __builtin_amdgcn_s_setprio(1);
            MFMA8(0, a0) MFMA8(1, a1)
            __builtin_amdgcn_s_setprio(0);
            __builtin_amdgcn_sched_barrier(0);
        }
        __builtin_amdgcn_s_barrier();

        // ---- phase 1: stage A-half1; A m2,m3 ----
        if (doStage) GL(aS1 + koff, St + dA1);
        {
            v4i a2 = *(const v4i*)(Sc + aOff + 2048);
            v4i a3 = *(const v4i*)(Sc + aOff + 3072);
            __builtin_amdgcn_sched_barrier(0);
            __builtin_amdgcn_s_setprio(1);
            MFMA8(2, a2) MFMA8(3, a3)
            __builtin_amdgcn_s_setprio(0);
            __builtin_amdgcn_sched_barrier(0);
        }
        __builtin_amdgcn_s_barrier();

        // ---- phase 2: stage B-half0; A m4,m5 ----
        if (doStage) GL(bS0 + koff, St + 16384 + dA0);
        {
            v4i a4 = *(const v4i*)(Sc + aOff + 4096);
            v4i a5 = *(const v4i*)(Sc + aOff + 5120);
            __builtin_amdgcn_sched_barrier(0);
            __builtin_amdgcn_s_setprio(1);
            MFMA8(4, a4) MFMA8(5, a5)
            __builtin_amdgcn_s_setprio(0);
            __builtin_amdgcn_sched_barrier(0);
        }
        __builtin_amdgcn_s_barrier();

        // ---- phase 3: stage B-half1; A m6,m7; counted-vmcnt boundary ----
        if (doStage) GL(bS1 + koff, St + 16384 + dA1);
        {
            v4i a6 = *(const v4i*)(Sc + aOff + 6144);
            v4i a7 = *(const v4i*)(Sc + aOff + 7168);
            __builtin_amdgcn_sched_barrier(0);
            __builtin_amdgcn_s_setprio(1);
            MFMA8(6, a6) MFMA8(7, a7)
            __builtin_amdgcn_s_setprio(0);
            __builtin_amdgcn_sched_barrier(0);
        }
        if (kt < 62) { asm volatile("s_waitcnt vmcnt(4)" ::: "memory"); }
        else         { asm volatile("s_waitcnt vmcnt(0)" ::: "memory"); }
        __builtin_amdgcn_s_barrier();

        cb = (cb == 2) ? 0 : cb + 1;
        sb = (sb == 2) ? 0 : sb + 1;
    }

    // epilogue: C/D layout col=l&15, row=(l>>4)*4+j (HW-verified round 0)
    const int gr0 = tm + wm + ch * 4;
    const int gc0 = tn + wn + i;
    float scl[4], zr[4], wsm[4];
#pragma unroll
    for (int n = 0; n < 4; ++n) {
        const int gc = gc0 + n * 16;
        scl[n] = scales[gc]; zr[n] = zeros[gc]; wsm[n] = wsumf[gc];
    }
#pragma unroll
    for (int m = 0; m < 8; ++m) {
#pragma unroll
        for (int j = 0; j < 4; ++j) {
            const int gr = gr0 + m * 16 + j;
            const float ra = sA[gr], rb = sB[gr], rc = sC[gr];
            float* orow = out + (size_t)gr * DIM_N;
#pragma unroll
            for (int n = 0; n < 4; ++n)
                orow[gc0 + n * 16] =
                    scl[n] * (ra * (float)acc[m][n][j] - rb * wsm[n] - rc * zr[n]);
        }
    }
}

// ---------------------------------------------------------------------------
extern "C" void kernel_launch(void* const* d_in, const int* in_sizes, int n_in,
                              void* d_out, int out_size, void* d_ws, size_t ws_size,
                              hipStream_t stream) {
    const float* x      = (const float*)d_in[0];
    const int*   w      = (const int*)d_in[1];
    const float* scales = (const float*)d_in[2];
    const float* zeros  = (const float*)d_in[3];
    float* out = (float*)d_out;

    uint8_t* ws = (uint8_t*)d_ws;
    int8_t* q  = (int8_t*)ws;                                  // 32 MiB
    int8_t* wq = (int8_t*)(ws + (size_t)TOK_M * DIM_K);        // 16 MiB
    float* fbuf = (float*)(ws + (size_t)TOK_M * DIM_K + (size_t)DIM_N * DIM_K);
    float* sA    = fbuf;
    float* sB    = fbuf + TOK_M;
    float* sC    = fbuf + 2 * TOK_M;
    float* wsumf = fbuf + 3 * TOK_M;

    k_pack_w<<<DIM_N, 256, 0, stream>>>(w, wq, wsumf);
    k_quant<<<TOK_M, 256, 0, stream>>>(x, q, sA, sB, sC);
    k_gemm<<<512, 512, 98304, stream>>>(q, wq, sA, sB, sC, wsumf, scales, zeros, out);
}

// Round 3
// 407.374 us; speedup vs baseline: 1.0657x; 1.0230x over previous
//
#include <hip/hip_runtime.h>
#include <stdint.h>

typedef int   v4i __attribute__((ext_vector_type(4)));
typedef float v4f __attribute__((ext_vector_type(4)));

#define TOK_M 8192   // B*S = 4*2048
#define DIM_K 4096   // IN
#define DIM_N 4096   // OUT

#define GL(src, dst)                                                                   \
  __builtin_amdgcn_global_load_lds((const __attribute__((address_space(1))) void*)(src), \
                                   (__attribute__((address_space(3))) void*)(dst), 16, 0, 0)

// ---------------------------------------------------------------------------
// Kernel 1: weight int32 -> int8 pack + per-row sums (fully coalesced)
// ---------------------------------------------------------------------------
__global__ __launch_bounds__(256) void k_pack_w(const int* __restrict__ w,
                                                int8_t* __restrict__ wq,
                                                float* __restrict__ wsumf) {
    __shared__ int sred[4];
    const int row = blockIdx.x;
    const int tid = threadIdx.x;
    const int4* src = (const int4*)(w + (size_t)row * DIM_K);
    unsigned* dst = (unsigned*)(wq + (size_t)row * DIM_K);
    int sum = 0;
#pragma unroll
    for (int c = 0; c < 4; ++c) {
        int4 iv = src[c * 256 + tid];
        sum += iv.x + iv.y + iv.z + iv.w;
        unsigned p = (unsigned)(iv.x & 255) | ((unsigned)(iv.y & 255) << 8) |
                     ((unsigned)(iv.z & 255) << 16) | ((unsigned)(iv.w & 255) << 24);
        dst[c * 256 + tid] = p;
    }
#pragma unroll
    for (int off = 32; off; off >>= 1) sum += __shfl_xor(sum, off);
    if ((tid & 63) == 0) sred[tid >> 6] = sum;
    __syncthreads();
    if (tid == 0) wsumf[row] = (float)(sred[0] + sred[1] + sred[2] + sred[3]);
}

// ---------------------------------------------------------------------------
// Kernel 2: per-token dynamic quant (coalesced chunked layout)
// ---------------------------------------------------------------------------
__global__ __launch_bounds__(256) void k_quant(const float* __restrict__ x,
                                               int8_t* __restrict__ q,
                                               float* __restrict__ sA,
                                               float* __restrict__ sB,
                                               float* __restrict__ sC) {
    __shared__ float redf[8];
    __shared__ int   redi[4];
    __shared__ float bcast[2];
    const int tok = blockIdx.x;
    const int tid = threadIdx.x;
    const v4f* xr = (const v4f*)(x + (size_t)tok * DIM_K);
    v4f v[4];
    float mn = 0.0f, mx = 0.0f;
#pragma unroll
    for (int c = 0; c < 4; ++c) {
        v[c] = xr[c * 256 + tid];
#pragma unroll
        for (int j = 0; j < 4; ++j) {
            mn = fminf(mn, v[c][j]);
            mx = fmaxf(mx, v[c][j]);
        }
    }
#pragma unroll
    for (int off = 32; off; off >>= 1) {
        mn = fminf(mn, __shfl_xor(mn, off));
        mx = fmaxf(mx, __shfl_xor(mx, off));
    }
    const int wid = tid >> 6;
    if ((tid & 63) == 0) { redf[wid] = mn; redf[4 + wid] = mx; }
    __syncthreads();
    if (tid == 0) {
        float m0 = fminf(fminf(redf[0], redf[1]), fminf(redf[2], redf[3]));
        float m1 = fmaxf(fmaxf(redf[4], redf[5]), fmaxf(redf[6], redf[7]));
        float scale = fmaxf((m1 - m0) / 255.0f, 1.1920928955078125e-07f);
        float zpf = -128.0f - rintf(m0 / scale);
        zpf = fminf(fmaxf(zpf, -128.0f), 127.0f);
        bcast[0] = scale; bcast[1] = zpf;
    }
    __syncthreads();
    const float scale = bcast[0];
    const float zpf   = bcast[1];
    const float inv   = 1.0f / scale;
    int qs = 0;
    unsigned* qo = (unsigned*)(q + (size_t)tok * DIM_K);
#pragma unroll
    for (int c = 0; c < 4; ++c) {
        unsigned p = 0;
#pragma unroll
        for (int j = 0; j < 4; ++j) {
            float qf = rintf(v[c][j] * inv) + zpf;
            qf = fminf(fmaxf(qf, -128.0f), 127.0f);
            int qi = (int)qf;
            qs += qi;
            p |= ((unsigned)(qi & 255)) << (8 * j);
        }
        qo[c * 256 + tid] = p;
    }
#pragma unroll
    for (int off = 32; off; off >>= 1) qs += __shfl_xor(qs, off);
    if ((tid & 63) == 0) redi[wid] = qs;
    __syncthreads();
    if (tid == 0) {
        int qtot = redi[0] + redi[1] + redi[2] + redi[3];
        sA[tok] = scale;
        sB[tok] = scale * zpf;
        sC[tok] = scale * ((float)qtot - 4096.0f * zpf);
    }
}

// ---------------------------------------------------------------------------
// Kernel 3: int8 GEMM 256x256, 8 waves, BK=64, triple-buffer, counted vmcnt.
// m201-style: 2 phases/K-tile, 16 MFMA per barrier section, ds_reads issued
// BEFORE the leading barrier (latency hides under barrier wait).
// ---------------------------------------------------------------------------
#define MM4(AF, M)                                                                  \
    acc[M][0] = __builtin_amdgcn_mfma_i32_16x16x64_i8(AF, bf0, acc[M][0], 0, 0, 0); \
    acc[M][1] = __builtin_amdgcn_mfma_i32_16x16x64_i8(AF, bf1, acc[M][1], 0, 0, 0); \
    acc[M][2] = __builtin_amdgcn_mfma_i32_16x16x64_i8(AF, bf2, acc[M][2], 0, 0, 0); \
    acc[M][3] = __builtin_amdgcn_mfma_i32_16x16x64_i8(AF, bf3, acc[M][3], 0, 0, 0);

__global__ __launch_bounds__(512, 2) void k_gemm(const int8_t* __restrict__ A,
                                                 const int8_t* __restrict__ B,
                                                 const float* __restrict__ sA,
                                                 const float* __restrict__ sB,
                                                 const float* __restrict__ sC,
                                                 const float* __restrict__ wsumf,
                                                 const float* __restrict__ scales,
                                                 const float* __restrict__ zeros,
                                                 float* __restrict__ out) {
    extern __shared__ int8_t lds[];   // 3 bufs x (A 16KB + B 16KB) = 96 KB
    const int tid = threadIdx.x;
    const int l = tid & 63;
    const int wid = tid >> 6;

    // T1: XCD swizzle with SQUARE per-XCD chunks. Tile grid 32(M) x 16(N);
    // each XCD owns an 8x8-tile chunk: A-panel 8MB + B-panel 8MB per XCD.
    const int xcd = blockIdx.x & 7;
    const int idx = blockIdx.x >> 3;                  // 0..63
    const int tm = ((xcd >> 1) * 8 + (idx & 7)) * 256;
    const int tn = ((xcd & 1) * 8 + (idx >> 3)) * 256;

    // staging: thread -> (row=tid>>2, chunk=tid&3); inverse T2 swizzle on the
    // GLOBAL source so LDS[row][pos] = global[row][pos ^ ((row>>1)&3)].
    const int sr  = tid >> 2;
    const int scg = (tid & 3) ^ ((tid >> 3) & 3);
    const int8_t* aS0 = A + (size_t)(tm + sr) * DIM_K + scg * 16;
    const int8_t* aS1 = A + (size_t)(tm + 128 + sr) * DIM_K + scg * 16;
    const int8_t* bS0 = B + (size_t)(tn + sr) * DIM_K + scg * 16;
    const int8_t* bS1 = B + (size_t)(tn + 128 + sr) * DIM_K + scg * 16;
    const int dA0 = tid * 16;
    const int dA1 = 8192 + tid * 16;

    // read addressing: row i = l&15, K-chunk ch = l>>4, T2-swizzled pos
    const int i  = l & 15;
    const int ch = l >> 4;
    const int pos = ch ^ ((i >> 1) & 3);
    const int wm = (wid >> 2) * 128;
    const int wn = (wid & 3) * 64;
    const int aOff = (wm + i) * 64 + pos * 16;           // + m*1024
    const int bOff = 16384 + (wn + i) * 64 + pos * 16;   // + n*1024

    v4i acc[8][4] = {};

    // prologue: stage K-tiles 0,1 into bufs 0,1
    GL(aS0, lds + dA0);          GL(aS1, lds + dA1);
    GL(bS0, lds + 16384 + dA0);  GL(bS1, lds + 16384 + dA1);
    GL(aS0 + 64, lds + 32768 + dA0);          GL(aS1 + 64, lds + 32768 + dA1);
    GL(bS0 + 64, lds + 32768 + 16384 + dA0);  GL(bS1 + 64, lds + 32768 + 16384 + dA1);
    asm volatile("s_waitcnt vmcnt(4)" ::: "memory");
    __builtin_amdgcn_s_barrier();

    int cb = 0, sb = 2;
    for (int kt = 0; kt < 64; ++kt) {
        const int koff = kt * 64 + 128;                // K byte offset of tile kt+2
        int8_t* Sc = lds + cb * 32768;
        int8_t* St = lds + sb * 32768;
        const bool doStage = (kt < 62);
        v4i af0, af1, af2, af3, bf0, bf1, bf2, bf3;

        // ---- phase 0: GL A(kt+2); read B n0-3 + A m0-3; barrier; 16 MFMA ----
        if (doStage) { GL(aS0 + koff, St + dA0); GL(aS1 + koff, St + dA1); }
        bf0 = *(const v4i*)(Sc + bOff);
        bf1 = *(const v4i*)(Sc + bOff + 1024);
        bf2 = *(const v4i*)(Sc + bOff + 2048);
        bf3 = *(const v4i*)(Sc + bOff + 3072);
        af0 = *(const v4i*)(Sc + aOff);
        af1 = *(const v4i*)(Sc + aOff + 1024);
        af2 = *(const v4i*)(Sc + aOff + 2048);
        af3 = *(const v4i*)(Sc + aOff + 3072);
        __builtin_amdgcn_sched_barrier(0);
        __builtin_amdgcn_s_barrier();
        __builtin_amdgcn_s_setprio(1);
        MM4(af0, 0) MM4(af1, 1) MM4(af2, 2) MM4(af3, 3)
        __builtin_amdgcn_s_setprio(0);
        __builtin_amdgcn_sched_barrier(0);
        __builtin_amdgcn_s_barrier();

        // ---- phase 1: GL B(kt+2); read A m4-7; barrier; 16 MFMA; vmcnt ----
        if (doStage) { GL(bS0 + koff, St + 16384 + dA0); GL(bS1 + koff, St + 16384 + dA1); }
        af0 = *(const v4i*)(Sc + aOff + 4096);
        af1 = *(const v4i*)(Sc + aOff + 5120);
        af2 = *(const v4i*)(Sc + aOff + 6144);
        af3 = *(const v4i*)(Sc + aOff + 7168);
        __builtin_amdgcn_sched_barrier(0);
        __builtin_amdgcn_s_barrier();
        __builtin_amdgcn_s_setprio(1);
        MM4(af0, 4) MM4(af1, 5) MM4(af2, 6) MM4(af3, 7)
        __builtin_amdgcn_s_setprio(0);
        __builtin_amdgcn_sched_barrier(0);
        if (kt < 62) { asm volatile("s_waitcnt vmcnt(4)" ::: "memory"); }
        else         { asm volatile("s_waitcnt vmcnt(0)" ::: "memory"); }
        __builtin_amdgcn_s_barrier();

        cb = (cb == 2) ? 0 : cb + 1;
        sb = (sb == 2) ? 0 : sb + 1;
    }

    // epilogue: C/D layout col=l&15, row=(l>>4)*4+j (HW-verified)
    const int gr0 = tm + wm + ch * 4;
    const int gc0 = tn + wn + i;
    float scl[4], zr[4], wsm[4];
#pragma unroll
    for (int n = 0; n < 4; ++n) {
        const int gc = gc0 + n * 16;
        scl[n] = scales[gc]; zr[n] = zeros[gc]; wsm[n] = wsumf[gc];
    }
#pragma unroll
    for (int m = 0; m < 8; ++m) {
#pragma unroll
        for (int j = 0; j < 4; ++j) {
            const int gr = gr0 + m * 16 + j;
            const float ra = sA[gr], rb = sB[gr], rc = sC[gr];
            float* orow = out + (size_t)gr * DIM_N;
#pragma unroll
            for (int n = 0; n < 4; ++n)
                orow[gc0 + n * 16] =
                    scl[n] * (ra * (float)acc[m][n][j] - rb * wsm[n] - rc * zr[n]);
        }
    }
}

// ---------------------------------------------------------------------------
extern "C" void kernel_launch(void* const* d_in, const int* in_sizes, int n_in,
                              void* d_out, int out_size, void* d_ws, size_t ws_size,
                              hipStream_t stream) {
    const float* x      = (const float*)d_in[0];
    const int*   w      = (const int*)d_in[1];
    const float* scales = (const float*)d_in[2];
    const float* zeros  = (const float*)d_in[3];
    float* out = (float*)d_out;

    uint8_t* ws = (uint8_t*)d_ws;
    int8_t* q  = (int8_t*)ws;                                  // 32 MiB
    int8_t* wq = (int8_t*)(ws + (size_t)TOK_M * DIM_K);        // 16 MiB
    float* fbuf = (float*)(ws + (size_t)TOK_M * DIM_K + (size_t)DIM_N * DIM_K);
    float* sA    = fbuf;
    float* sB    = fbuf + TOK_M;
    float* sC    = fbuf + 2 * TOK_M;
    float* wsumf = fbuf + 3 * TOK_M;

    k_pack_w<<<DIM_N, 256, 0, stream>>>(w, wq, wsumf);
    k_quant<<<TOK_M, 256, 0, stream>>>(x, q, sA, sB, sC);
    k_gemm<<<512, 512, 98304, stream>>>(q, wq, sA, sB, sC, wsumf, scales, zeros, out);
}